// Round 4
// baseline (720.843 us; speedup 1.0000x reference)
//
#include <hip/hip_runtime.h>

#define CIN  512
#define COUT 512
#define LAT  512
#define NB   16

typedef __attribute__((ext_vector_type(8))) short bf16x8;
typedef __attribute__((ext_vector_type(4))) float f32x4;

__device__ __forceinline__ unsigned short f2bf(float f) {
    unsigned int u = __builtin_bit_cast(unsigned int, f);
    u += 0x7FFFu + ((u >> 16) & 1u);
    return (unsigned short)(u >> 16);
}

// ---------- s[b][ci] = w[b,:] . affine_w[ci,:] + ab[ci] + 1 ----------
__global__ void k_style(const float* __restrict__ w, const float* __restrict__ aw,
                        const float* __restrict__ ab, float* __restrict__ s) {
    int b = blockIdx.x, ci = threadIdx.x;
    __shared__ float wl[LAT];
    wl[ci] = w[b * LAT + ci];
    __syncthreads();
    const float4* awr = (const float4*)(aw + (size_t)ci * LAT);
    float acc = 0.f;
#pragma unroll 4
    for (int l = 0; l < LAT / 4; ++l) {
        float4 a4 = awr[l];
        const float* wp = &wl[l * 4];
        acc += a4.x * wp[0] + a4.y * wp[1] + a4.z * wp[2] + a4.w * wp[3];
    }
    s[b * CIN + ci] = acc + ab[ci] + 1.0f;
}

// ---------- wsq[co][ci] = sum_k weight[co,ci,k]^2 ----------
__global__ void k_wsq(const float* __restrict__ weight, float* __restrict__ wsq) {
    int co = blockIdx.x, ci = threadIdx.x;
    const float* p = weight + ((size_t)co * CIN + ci) * 9;
    float a = 0.f;
#pragma unroll
    for (int k = 0; k < 9; ++k) a += p[k] * p[k];
    wsq[co * CIN + ci] = a;
}

// ---------- d[b][co] = rsqrt(sum_ci s^2 * wsq + 1e-8) ----------
__global__ void k_demod(const float* __restrict__ s, const float* __restrict__ wsq,
                        float* __restrict__ d) {
    int b = blockIdx.x, co = threadIdx.x;
    __shared__ float s2[CIN];
    float sv = s[b * CIN + co];
    s2[co] = sv * sv;
    __syncthreads();
    const float4* wr = (const float4*)(wsq + (size_t)co * CIN);
    float acc = 0.f;
#pragma unroll 4
    for (int i = 0; i < CIN / 4; ++i) {
        float4 v = wr[i];
        const float* sp = &s2[i * 4];
        acc += v.x * sp[0] + v.y * sp[1] + v.z * sp[2] + v.w * sp[3];
    }
    d[b * COUT + co] = rsqrtf(acc + 1e-8f);
}

// ---------- A9[m=co*9+kk][ci] = bf16(weight[co][ci][kk]) ----------
__global__ void k_prepw(const float* __restrict__ weight, unsigned short* __restrict__ A9) {
    int co = blockIdx.x, t = threadIdx.x;
    __shared__ float wl[CIN * 9];
    const float* wp = weight + (size_t)co * CIN * 9;
    for (int i = t; i < CIN * 9; i += 256) wl[i] = wp[i];
    __syncthreads();
    unsigned short* ap = A9 + (size_t)co * 9 * CIN;
    for (int i = t; i < CIN * 9; i += 256) {
        int kk = i >> 9, ci = i & 511;
        ap[i] = f2bf(wl[ci * 9 + kk]);
    }
}

// ---------- XT[b][p][ci] = bf16(s[b][ci] * x[b][ci][p]) ----------
__global__ void k_prepx(const float* __restrict__ x, const float* __restrict__ s,
                        unsigned short* __restrict__ XT) {
    int blk = blockIdx.x;                 // 16b * 16pt * 8ct = 2048
    int b = blk >> 7, pt = (blk >> 3) & 15, ct = blk & 7;
    int p0 = pt * 64, ci0 = ct * 64;
    __shared__ float xt[64][65];
    __shared__ float ss[64];
    int t = threadIdx.x;
    if (t < 64) ss[t] = s[b * CIN + ci0 + t];
    const float* xb = x + ((size_t)(b * CIN + ci0)) * 1024 + p0;
#pragma unroll
    for (int rr = 0; rr < 4; ++rr) {
        int i = rr * 16 + (t >> 4), j = (t & 15) * 4;
        float4 v = *(const float4*)(xb + (size_t)i * 1024 + j);
        xt[i][j] = v.x; xt[i][j + 1] = v.y; xt[i][j + 2] = v.z; xt[i][j + 3] = v.w;
    }
    __syncthreads();
    unsigned short* xo = XT + ((size_t)(b * 1024 + p0)) * CIN + ci0;
#pragma unroll
    for (int rr = 0; rr < 4; ++rr) {
        int jj = rr * 16 + (t >> 4);
        int c4 = (t & 15) * 4;
        ushort4 o;
        o.x = f2bf(xt[c4][jj] * ss[c4]);
        o.y = f2bf(xt[c4 + 1][jj] * ss[c4 + 1]);
        o.z = f2bf(xt[c4 + 2][jj] * ss[c4 + 2]);
        o.w = f2bf(xt[c4 + 3][jj] * ss[c4 + 3]);
        *(ushort4*)(xo + (size_t)jj * CIN + c4) = o;
    }
}

// ---------- bf16 GEMM: C[4608][Ns] fp16 = A9[4608][512] x XT[Ns][512]^T ----------
// 128M x 256N, BK=32, 512 thr (2x4 waves), double-buffered LDS, 2-phase schedule.
__device__ __forceinline__ void gload16(const void* g, void* l) {
    __builtin_amdgcn_global_load_lds(
        (const __attribute__((address_space(1))) void*)g,
        (__attribute__((address_space(3))) void*)l, 16, 0, 0);
}

__launch_bounds__(512, 6)
__global__ void k_gemm(const unsigned short* __restrict__ A9,
                       const unsigned short* __restrict__ XT,
                       _Float16* __restrict__ C, int Ns) {
    __shared__ unsigned short smem[24576];   // 48KB = 2 buffers x (A 8KB + B 16KB)
    const int t = threadIdx.x;
    const int bm = blockIdx.x, bn = blockIdx.y;
    const int w = t >> 6, lane = t & 63;
    const int wr = w >> 2, wc = w & 3;
    const int lrow = lane & 15;

    // staging: thread t stages 16B chunk t of A (8KB) and chunks t, t+512 of B (16KB)
    const int rowT = t >> 2;                                        // 0..127
    const unsigned kbT = ((unsigned)(t & 3) << 4) ^ ((((unsigned)rowT >> 1) & 3u) << 4);
    const char* pA  = (const char*)A9 + (size_t)(bm * 128 + rowT) * 1024 + kbT;
    const char* pB1 = (const char*)XT + (size_t)(bn * 256 + rowT) * 1024 + kbT;
    const char* pB2 = pB1 + (size_t)128 * 1024;
    char* dA  = (char*)smem + (w << 10);       // wave-uniform base (+lane*16 implicit)
    char* dB1 = dA + 8192;
    char* dB2 = dA + 16384;

    // fragment read offsets (swizzled, 2-way conflict = free)
    const unsigned kbx = ((unsigned)(lane >> 4) << 4) ^ ((((unsigned)lrow >> 1) & 3u) << 4);
    unsigned offA[4], offB[4];
#pragma unroll
    for (int f = 0; f < 4; ++f) {
        offA[f] = (unsigned)((wr * 64 + f * 16 + lrow) * 64) + kbx;
        offB[f] = 8192u + (unsigned)((wc * 64 + f * 16 + lrow) * 64) + kbx;
    }

    f32x4 acc[4][4];
#pragma unroll
    for (int i = 0; i < 4; ++i)
#pragma unroll
        for (int j = 0; j < 4; ++j) acc[i][j] = (f32x4){0.f, 0.f, 0.f, 0.f};

    // prologue: stage K-step 0 into buffer 0
    gload16(pA, dA); gload16(pB1, dB1); gload16(pB2, dB2);
    pA += 64; pB1 += 64; pB2 += 64;

    int selOff = 0;
    for (int it = 0; it < 16; ++it) {          // K = 512, BK = 32
        __syncthreads();                       // buf[sel] staged & safe to read
        if (it < 15) {                         // stage next tile into other buffer
            int nOff = selOff ^ 24576;
            gload16(pA, dA + nOff); gload16(pB1, dB1 + nOff); gload16(pB2, dB2 + nOff);
            pA += 64; pB1 += 64; pB2 += 64;
        }
        const char* rb = (const char*)smem + selOff;
        bf16x8 a[4], b[4];
#pragma unroll
        for (int f = 0; f < 4; ++f) a[f] = *(const bf16x8*)(rb + offA[f]);
#pragma unroll
        for (int f = 0; f < 4; ++f) b[f] = *(const bf16x8*)(rb + offB[f]);
#pragma unroll
        for (int mf = 0; mf < 4; ++mf)
#pragma unroll
            for (int nf = 0; nf < 4; ++nf)
                acc[mf][nf] = __builtin_amdgcn_mfma_f32_16x16x32_bf16(
                    a[mf], b[nf], acc[mf][nf], 0, 0, 0);
        selOff ^= 24576;
    }

    const int mg0 = bm * 128 + wr * 64 + (lane >> 4) * 4;
    const int ng0 = bn * 256 + wc * 64 + lrow;
#pragma unroll
    for (int mf = 0; mf < 4; ++mf)
#pragma unroll
        for (int j = 0; j < 4; ++j) {
            size_t row = (size_t)(mg0 + mf * 16 + j) * (size_t)Ns;
#pragma unroll
            for (int nf = 0; nf < 4; ++nf)
                C[row + ng0 + nf * 16] = (_Float16)acc[mf][nf][j];
        }
}

// ---------- fused scatter+blur, 2-stage linear (H then vertical), 2 barriers ----------
// E[r]=T0[r]+T2[r-1], O[r]=T1[r]  (horizontal y cols 2r, 2r+1)
// H[ky][iy][px] = 4-tap blur over interleaved E/O at px
// out[py][px] = 6-term vertical combine of H (+halo rows), * d + bias
__device__ __forceinline__ float2 up2(unsigned u) {
    _Float16 lo = __builtin_bit_cast(_Float16, (unsigned short)(u & 0xffffu));
    _Float16 hi = __builtin_bit_cast(_Float16, (unsigned short)(u >> 16));
    return make_float2((float)lo, (float)hi);
}

__launch_bounds__(512, 6)
__global__ void k_post(const _Float16* __restrict__ C, const float* __restrict__ dmod,
                       const float* __restrict__ bias, float* __restrict__ out,
                       int b0, int Ns) {
    const int blk = blockIdx.x;
    const int bl = blk >> 9, co = blk & 511, b = b0 + bl;
    const int t = threadIdx.x;
    __shared__ __align__(16) char pool[31904];
    _Float16* taps = (_Float16*)pool;            // 9 planes x 32x32 (stride 32), 18432B
    // H at pool+18432: 3 planes x 34 rows x stride 66 fp16 (rows 0 and 33 = zero halo)

    // ---- P0: issue tap loads, zero H halo rows, write taps (linear, aligned) ----
    const char* Cb = (const char*)(C + (size_t)(co * 9) * (size_t)Ns + bl * 1024);
    const size_t nsb = (size_t)Ns * 2;
    int4 v0 = *(const int4*)(Cb + (size_t)(t >> 7) * nsb + (t & 127) * 16);
    int4 v1 = *(const int4*)(Cb + (size_t)((t + 512) >> 7) * nsb + ((t + 512) & 127) * 16);
    int4 v2;
    if (t < 128) v2 = *(const int4*)(Cb + (size_t)((t + 1024) >> 7) * nsb + ((t + 1024) & 127) * 16);
    if (t < 198) {   // zero H halo rows (3 planes x rows {0,33} x 33 u32)
        int ky = t / 66, rem = t % 66;
        int rowoff = (rem < 33) ? 0 : 4356;      // 33*132
        int ci = (rem < 33) ? rem : rem - 33;
        ((unsigned*)(pool + 18432 + ky * 4488 + rowoff))[ci] = 0u;
    }
    *(int4*)(pool + t * 16) = v0;
    *(int4*)(pool + 8192 + t * 16) = v1;
    if (t < 128) *(int4*)(pool + 16384 + t * 16) = v2;
    __syncthreads();

    // ---- P1: build H (3 ky x 32 iy x 16 quad-cols = 1536 tasks) ----
#pragma unroll
    for (int i = 0; i < 3; ++i) {
        int tau = t + 512 * i;
        int ky = tau >> 9, rem = tau & 511;
        int iy = rem >> 4, q = rem & 15, c = 2 * q;
        const _Float16* T0 = taps + (ky * 3) * 1024 + iy * 32;
        const _Float16* T1 = T0 + 1024;
        const _Float16* T2 = T0 + 2048;
        int cm = (q > 0) ? c - 1 : 0;
        int cp = (q < 15) ? c + 2 : 31;
        float t0a = (float)T0[c], t0b = (float)T0[c + 1];
        float t1a = (float)T1[c], t1b = (float)T1[c + 1];
        float t2a = (float)T2[c], t2b = (float)T2[c + 1];
        float t1m = (q > 0) ? (float)T1[cm] : 0.f;
        float t2m = (q > 0) ? (float)T2[cm] : 0.f;
        float t0c = (q < 15) ? (float)T0[cp] : 0.f;
        float t1c = (q < 15) ? (float)T1[cp] : 0.f;
        float E0 = t0a + t2m, E1 = t0b + t2a, E2 = t0c + t2b;
        float h0 = 0.25f * t1m + 0.75f * E0 + 0.75f * t1a + 0.25f * E1;
        float h1 = 0.25f * E0 + 0.75f * t1a + 0.75f * E1 + 0.25f * t1b;
        float h2 = 0.25f * t1a + 0.75f * E1 + 0.75f * t1b + 0.25f * E2;
        float h3 = 0.25f * E1 + 0.75f * t1b + 0.75f * E2 + 0.25f * t1c;
        unsigned* Hrow = (unsigned*)(pool + 18432 + ky * 4488 + (iy + 1) * 132);
        unsigned p01 = (unsigned)__builtin_bit_cast(unsigned short, (_Float16)h0) |
                       ((unsigned)__builtin_bit_cast(unsigned short, (_Float16)h1) << 16);
        unsigned p23 = (unsigned)__builtin_bit_cast(unsigned short, (_Float16)h2) |
                       ((unsigned)__builtin_bit_cast(unsigned short, (_Float16)h3) << 16);
        Hrow[2 * q] = p01;
        Hrow[2 * q + 1] = p23;
    }
    __syncthreads();

    // ---- P2: vertical combine + demod + bias (64 py x 32 px-pairs = 2048 tasks) ----
    const float dv = dmod[b * COUT + co];
    const float bv = bias[co];
    float* oplane = out + ((size_t)b * COUT + co) * 4096;
#pragma unroll
    for (int i = 0; i < 4; ++i) {
        int tau = t + 512 * i;
        int py = tau >> 5, pr = tau & 31, px0 = 2 * pr;
        int m = py >> 1, par = py & 1;
        const char* Hb = pool + 18432 + px0 * 2;
        float2 h0a = up2(*(const unsigned*)(Hb + (m + 1) * 132));
        float2 h0b = up2(*(const unsigned*)(Hb + (m + 2) * 132));
        int r1 = m + par;
        float2 h1a = up2(*(const unsigned*)(Hb + 4488 + r1 * 132));
        float2 h1b = up2(*(const unsigned*)(Hb + 4488 + (r1 + 1) * 132));
        float2 h2a = up2(*(const unsigned*)(Hb + 8976 + m * 132));
        float2 h2b = up2(*(const unsigned*)(Hb + 8976 + (m + 1) * 132));
        float wP = par ? 0.25f : 0.75f;   // H0/H2 first weight
        float wQ = par ? 0.75f : 0.25f;
        float s0 = wP * h0a.x + wQ * h0b.x + wQ * h1a.x + wP * h1b.x + wP * h2a.x + wQ * h2b.x;
        float s1 = wP * h0a.y + wQ * h0b.y + wQ * h1a.y + wP * h1b.y + wP * h2a.y + wQ * h2b.y;
        float2 o;
        o.x = fmaf(dv, s0, bv);
        o.y = fmaf(dv, s1, bv);
        *(float2*)(oplane + py * 64 + px0) = o;
    }
}

extern "C" void kernel_launch(void* const* d_in, const int* in_sizes, int n_in,
                              void* d_out, int out_size, void* d_ws, size_t ws_size,
                              hipStream_t stream) {
    const float* x      = (const float*)d_in[0];
    const float* w      = (const float*)d_in[1];
    const float* weight = (const float*)d_in[2];
    const float* bias   = (const float*)d_in[3];
    const float* aw     = (const float*)d_in[4];
    const float* ab     = (const float*)d_in[5];
    float* out = (float*)d_out;

    char* wsb = (char*)d_ws;
    float* s            = (float*)wsb;                         // 32 KB
    float* dmod         = (float*)(wsb + 32768);               // 32 KB
    float* wsq          = (float*)(wsb + 65536);               // 1 MB
    unsigned short* A9  = (unsigned short*)(wsb + 1114112);    // 4.5 MB
    unsigned short* XT  = (unsigned short*)(wsb + 5832704);    // 16 MB
    _Float16* C         = (_Float16*)(wsb + 22609920);
    const size_t cbase  = 22609920;

    size_t avail = ws_size > cbase ? ws_size - cbase : 0;
    int nbc = 8;                                    // batches per chunk (C chunk L3-fits)
    while (nbc > 1 && (size_t)4608 * 1024 * (size_t)nbc * 2 > avail) nbc >>= 1;

    k_style<<<NB, 512, 0, stream>>>(w, aw, ab, s);
    k_wsq<<<COUT, 512, 0, stream>>>(weight, wsq);
    k_demod<<<NB, 512, 0, stream>>>(s, wsq, dmod);
    k_prepw<<<COUT, 256, 0, stream>>>(weight, A9);
    k_prepx<<<2048, 256, 0, stream>>>(x, s, XT);

    const int Ns = nbc * 1024;
    for (int bb = 0; bb < NB; bb += nbc) {
        k_gemm<<<dim3(36, nbc * 4), 512, 0, stream>>>(A9, XT + (size_t)bb * 1024 * CIN, C, Ns);
        k_post<<<nbc * 512, 512, 0, stream>>>(C, dmod, bias, out, bb, Ns);
    }
}